// Round 1
// baseline (221.749 us; speedup 1.0000x reference)
//
#include <hip/hip_runtime.h>
#include <math.h>

// GaussianMixtureLayer: N=4194304 points (D=2), K=32 isotropic components.
// Outputs: mix_lp (N,) then comp_lp (N,32), concatenated float32.
// Memory-bound: ~587 MB traffic -> ~93 us floor at 6.3 TB/s.

constexpr int KCOMP = 32;
constexpr float NEG_D_HALF_LOG2PI = -1.8378770664093453f; // -0.5*D*log(2pi), D=2
constexpr float LOG_K = 3.4657359027997265f;              // log(32)

__global__ __launch_bounds__(256) void gmm_kernel(
    const float* __restrict__ x,      // (N,2)
    const float* __restrict__ mu,     // (32,2)
    const float* __restrict__ sigma,  // (32,1)
    float* __restrict__ out,          // mix_lp (N) ++ comp_lp (N*32)
    int N)
{
    // Per-component constants, computed once per block into LDS.
    // cst[k] = {mu_x, mu_y, a = -0.5/s^2, c = -2*log(s) - log(2pi)}
    __shared__ float4 cst[KCOMP];
    if (threadIdx.x < KCOMP) {
        int k = threadIdx.x;
        float s = fabsf(sigma[k]) + 1e-5f;
        float a = -0.5f / (s * s);
        float c = -2.0f * __logf(s) + NEG_D_HALF_LOG2PI;
        cst[k] = make_float4(mu[2 * k], mu[2 * k + 1], a, c);
    }
    __syncthreads();

    float* __restrict__ mix_lp = out;
    float* __restrict__ comp_lp = out + (size_t)N;
    const float2* __restrict__ xp = (const float2*)x;

    const int stride = gridDim.x * blockDim.x;
    for (int n = blockIdx.x * blockDim.x + threadIdx.x; n < N; n += stride) {
        const float2 xv = xp[n];  // 8B coalesced load per lane

        float comp[KCOMP];
        float m = -INFINITY;
        #pragma unroll
        for (int k = 0; k < KCOMP; ++k) {
            const float4 cs = cst[k];  // broadcast ds_read_b128 (same addr all lanes)
            const float dx = xv.x - cs.x;
            const float dy = xv.y - cs.y;
            const float v = fmaf(fmaf(dy, dy, dx * dx), cs.z, cs.w);
            comp[k] = v;
            m = fmaxf(m, v);
        }

        float sum = 0.0f;
        #pragma unroll
        for (int k = 0; k < KCOMP; ++k) {
            sum += __expf(comp[k] - m);
        }
        mix_lp[n] = m + __logf(sum) - LOG_K;

        // 128B contiguous row per point, 8x float4 stores.
        float4* __restrict__ dst = (float4*)(comp_lp + (size_t)n * KCOMP);
        #pragma unroll
        for (int q = 0; q < 8; ++q) {
            dst[q] = make_float4(comp[4 * q], comp[4 * q + 1],
                                 comp[4 * q + 2], comp[4 * q + 3]);
        }
    }
}

extern "C" void kernel_launch(void* const* d_in, const int* in_sizes, int n_in,
                              void* d_out, int out_size, void* d_ws, size_t ws_size,
                              hipStream_t stream) {
    const float* x     = (const float*)d_in[0];
    const float* mu    = (const float*)d_in[1];
    const float* sigma = (const float*)d_in[2];
    float* out = (float*)d_out;

    const int N = in_sizes[0] / 2;  // inputs is (N, 2)

    const int block = 256;
    int grid = (N + block - 1) / block;
    if (grid > 2048) grid = 2048;  // grid-stride: ~8 points/thread

    gmm_kernel<<<grid, block, 0, stream>>>(x, mu, sigma, out, N);
}

// Round 2
// 152.539 us; speedup vs baseline: 1.4537x; 1.4537x over previous
//
#include <hip/hip_runtime.h>
#include <math.h>

// GaussianMixtureLayer: N=4194304 points (D=2), K=32 isotropic components.
// Outputs: mix_lp (N,) then comp_lp (N,32), concatenated float32.
// Memory-bound: ~587 MB traffic -> ~93 us floor at 6.3 TB/s.
//
// Layout: 8 lanes per point. Lane j = tid&7 owns components 4j..4j+3, whose
// constants live in registers (loaded once). comp_lp store address for
// thread i is base + 4*i floats -> fully coalesced 1KB per wave store.

constexpr float NEG_D_HALF_LOG2PI = -1.8378770664093453f; // -0.5*D*log(2pi), D=2
constexpr float LOG_K = 3.4657359027997265f;              // log(32)

__global__ __launch_bounds__(256) void gmm_kernel(
    const float* __restrict__ x,      // (N,2)
    const float* __restrict__ mu,     // (32,2)
    const float* __restrict__ sigma,  // (32,1)
    float* __restrict__ out,          // mix_lp (N) ++ comp_lp (N*32)
    int N)
{
    const int tid = threadIdx.x;
    const int j   = tid & 7;    // component sub-group: owns k = 4j..4j+3
    const int pg  = tid >> 3;   // point index within the block's 32-point tile

    // Per-lane component constants, in registers for the whole kernel.
    float mx[4], my[4], aa[4], cc[4];
    #pragma unroll
    for (int q = 0; q < 4; ++q) {
        const int k = j * 4 + q;
        const float s = fabsf(sigma[k]) + 1e-5f;
        mx[q] = mu[2 * k];
        my[q] = mu[2 * k + 1];
        aa[q] = -0.5f / (s * s);
        cc[q] = -2.0f * __logf(s) + NEG_D_HALF_LOG2PI;
    }

    float* __restrict__ mix_lp  = out;
    float* __restrict__ comp_lp = out + (size_t)N;
    const float2* __restrict__ xp = (const float2*)x;

    const int pts_per_blk = blockDim.x >> 3;          // 32 points per block-iter
    const int stride = gridDim.x * pts_per_blk;

    for (int p0 = blockIdx.x * pts_per_blk; p0 < N; p0 += stride) {
        const int p = p0 + pg;
        const float2 xv = xp[p];  // 8 lanes share one 8B read (L1 broadcast)

        float comp[4];
        float m = -INFINITY;
        #pragma unroll
        for (int q = 0; q < 4; ++q) {
            const float dx = xv.x - mx[q];
            const float dy = xv.y - my[q];
            const float v = fmaf(fmaf(dy, dy, dx * dx), aa[q], cc[q]);
            comp[q] = v;
            m = fmaxf(m, v);
        }
        // max over the 8-lane group
        m = fmaxf(m, __shfl_xor(m, 1, 64));
        m = fmaxf(m, __shfl_xor(m, 2, 64));
        m = fmaxf(m, __shfl_xor(m, 4, 64));

        float sum = __expf(comp[0] - m) + __expf(comp[1] - m)
                  + __expf(comp[2] - m) + __expf(comp[3] - m);
        sum += __shfl_xor(sum, 1, 64);
        sum += __shfl_xor(sum, 2, 64);
        sum += __shfl_xor(sum, 4, 64);

        if (j == 0) mix_lp[p] = m + __logf(sum) - LOG_K;

        // thread i in wave stores at (p0*32 + 4*i) floats -> contiguous 1KB/wave
        float4* __restrict__ dst = (float4*)(comp_lp + (size_t)p * 32 + j * 4);
        *dst = make_float4(comp[0], comp[1], comp[2], comp[3]);
    }
}

extern "C" void kernel_launch(void* const* d_in, const int* in_sizes, int n_in,
                              void* d_out, int out_size, void* d_ws, size_t ws_size,
                              hipStream_t stream) {
    const float* x     = (const float*)d_in[0];
    const float* mu    = (const float*)d_in[1];
    const float* sigma = (const float*)d_in[2];
    float* out = (float*)d_out;

    const int N = in_sizes[0] / 2;  // inputs is (N, 2)

    const int block = 256;           // 32 points per block iteration
    const int grid = 2048;           // 32 waves/CU, grid-stride over N/32 tiles

    gmm_kernel<<<grid, block, 0, stream>>>(x, mu, sigma, out, N);
}

// Round 3
// 139.143 us; speedup vs baseline: 1.5937x; 1.0963x over previous
//
#include <hip/hip_runtime.h>
#include <math.h>

// GaussianMixtureLayer: N=4194304 points (D=2), K=32 isotropic components.
// Outputs: mix_lp (N,) then comp_lp (N,32), concatenated float32.
// Memory-bound: ~587 MB traffic -> ~90 us floor at fill-rate 6.6 TB/s.
//
// Layout: 8 lanes per point; lane j=tid&7 owns components 4j..4j+3 in regs.
// Thread i's comp_lp store address = base + 16B*i -> 1KB contiguous per wave.
// R3: 2 point-tiles per loop iteration (2 independent chains -> 2x MLP),
// nontemporal loads/stores (write-once streams skip cache allocation).

constexpr float NEG_D_HALF_LOG2PI = -1.8378770664093453f; // -0.5*D*log(2pi), D=2
constexpr float LOG_K = 3.4657359027997265f;              // log(32)

typedef float vf2 __attribute__((ext_vector_type(2)));
typedef float vf4 __attribute__((ext_vector_type(4)));

__global__ __launch_bounds__(256) void gmm_kernel(
    const float* __restrict__ x,      // (N,2)
    const float* __restrict__ mu,     // (32,2)
    const float* __restrict__ sigma,  // (32,1)
    float* __restrict__ out,          // mix_lp (N) ++ comp_lp (N*32)
    int N)
{
    const int tid = threadIdx.x;
    const int j   = tid & 7;    // component sub-group: owns k = 4j..4j+3
    const int pg  = tid >> 3;   // point index within a 32-point tile

    // Per-lane component constants, in registers for the whole kernel.
    float mx[4], my[4], aa[4], cc[4];
    #pragma unroll
    for (int q = 0; q < 4; ++q) {
        const int k = j * 4 + q;
        const float s = fabsf(sigma[k]) + 1e-5f;
        mx[q] = mu[2 * k];
        my[q] = mu[2 * k + 1];
        aa[q] = -0.5f / (s * s);
        cc[q] = -2.0f * __logf(s) + NEG_D_HALF_LOG2PI;
    }

    float* __restrict__ mix_lp  = out;
    float* __restrict__ comp_lp = out + (size_t)N;
    const vf2* __restrict__ xp = (const vf2*)x;

    const int stride = gridDim.x * 64;  // 2 tiles of 32 points per block-iter

    for (int p0 = blockIdx.x * 64; p0 < N; p0 += stride) {
        const int pA = p0 + pg;
        const int pB = p0 + 32 + pg;
        const bool hasB = (pB < N);

        // Issue both streaming loads up front (2 loads in flight).
        const vf2 xa = __builtin_nontemporal_load(&xp[pA]);
        const vf2 xb = hasB ? __builtin_nontemporal_load(&xp[pB])
                            : (vf2){0.0f, 0.0f};

        float ca[4], cb[4];
        float ma = -INFINITY, mb = -INFINITY;
        #pragma unroll
        for (int q = 0; q < 4; ++q) {
            const float dxa = xa.x - mx[q], dya = xa.y - my[q];
            const float dxb = xb.x - mx[q], dyb = xb.y - my[q];
            const float va = fmaf(fmaf(dya, dya, dxa * dxa), aa[q], cc[q]);
            const float vb = fmaf(fmaf(dyb, dyb, dxb * dxb), aa[q], cc[q]);
            ca[q] = va; ma = fmaxf(ma, va);
            cb[q] = vb; mb = fmaxf(mb, vb);
        }

        // Two independent 8-lane butterfly max-reductions, interleaved.
        ma = fmaxf(ma, __shfl_xor(ma, 1, 64));
        mb = fmaxf(mb, __shfl_xor(mb, 1, 64));
        ma = fmaxf(ma, __shfl_xor(ma, 2, 64));
        mb = fmaxf(mb, __shfl_xor(mb, 2, 64));
        ma = fmaxf(ma, __shfl_xor(ma, 4, 64));
        mb = fmaxf(mb, __shfl_xor(mb, 4, 64));

        float sa = __expf(ca[0] - ma) + __expf(ca[1] - ma)
                 + __expf(ca[2] - ma) + __expf(ca[3] - ma);
        float sb = __expf(cb[0] - mb) + __expf(cb[1] - mb)
                 + __expf(cb[2] - mb) + __expf(cb[3] - mb);
        sa += __shfl_xor(sa, 1, 64);
        sb += __shfl_xor(sb, 1, 64);
        sa += __shfl_xor(sa, 2, 64);
        sb += __shfl_xor(sb, 2, 64);
        sa += __shfl_xor(sa, 4, 64);
        sb += __shfl_xor(sb, 4, 64);

        if (j == 0) {
            __builtin_nontemporal_store(ma + __logf(sa) - LOG_K, &mix_lp[pA]);
            if (hasB)
                __builtin_nontemporal_store(mb + __logf(sb) - LOG_K, &mix_lp[pB]);
        }

        // thread i in wave stores 16B at +16B*i -> contiguous 1KB per wave instr
        vf4* __restrict__ dA = (vf4*)(comp_lp + (size_t)pA * 32 + j * 4);
        __builtin_nontemporal_store((vf4){ca[0], ca[1], ca[2], ca[3]}, dA);
        if (hasB) {
            vf4* __restrict__ dB = (vf4*)(comp_lp + (size_t)pB * 32 + j * 4);
            __builtin_nontemporal_store((vf4){cb[0], cb[1], cb[2], cb[3]}, dB);
        }
    }
}

extern "C" void kernel_launch(void* const* d_in, const int* in_sizes, int n_in,
                              void* d_out, int out_size, void* d_ws, size_t ws_size,
                              hipStream_t stream) {
    const float* x     = (const float*)d_in[0];
    const float* mu    = (const float*)d_in[1];
    const float* sigma = (const float*)d_in[2];
    float* out = (float*)d_out;

    const int N = in_sizes[0] / 2;  // inputs is (N, 2)

    const int block = 256;           // 64 points per block iteration
    const int grid = 2048;           // 8 blocks/CU, grid-stride (32 iters)

    gmm_kernel<<<grid, block, 0, stream>>>(x, mu, sigma, out, N);
}